// Round 8
// baseline (307.095 us; speedup 1.0000x reference)
//
#include <hip/hip_runtime.h>
#include <float.h>

#define TPB 512
#define KTOP 32
#define BIN_CAP 1024
#define NIT 12   // quads/thread in registers; capacity = 4*NIT*TPB = 24576 elems/segment

// Output buffer is f32; harness compares after bf16-casting both sides.
// Sentinel must bf16-round FINITE: 0xFF7F0000 -> bf16 0xFF7F.
#define SENT_U32 0xFF7F0000u
#define VCLAMP 3.0e38f

__device__ __forceinline__ unsigned int f2u(float f){
  unsigned int u = __float_as_uint(f);
  return (u & 0x80000000u) ? ~u : (u | 0x80000000u);
}

// suffix-sum of hist by 256 groups into gsum; returns total. TPB may exceed 256.
__device__ int suffix_total(int* hist, int NB, int* gsum, int tid){
  int GS = NB >> 8;
  if (tid < 256){
    int p = 0, base = tid * GS;
    for (int j = 0; j < GS; ++j) p += hist[base + j];
    gsum[tid] = p;
  }
  __syncthreads();
  for (int d = 1; d < 256; d <<= 1){
    int v = 0;
    if (tid < 256 && tid + d < 256) v = gsum[tid + d];
    __syncthreads();
    if (tid < 256) gsum[tid] += v;
    __syncthreads();
  }
  return gsum[0];
}

// find bin b with above(b) < R <= above(b)+hist[b]; requires 1 <= R <= gsum[0]
__device__ int find_bin(int* hist, int NB, int* gsum, int R, int* s2, int tid,
                        int* above_out){
  int GS = NB >> 8;
  if (tid < 256){
    int St  = gsum[tid];
    int St1 = (tid < 255) ? gsum[tid + 1] : 0;
    if (R > St1 && R <= St) s2[0] = tid;   // unique writer (gsum non-increasing)
  }
  __syncthreads();
  if (tid == 0){
    int G = s2[0];
    int above = (G < 255) ? gsum[G + 1] : 0;
    int b = (G + 1) * GS - 1;
    for (; b > G * GS; --b){
      int h = hist[b];
      if (above + h >= R) break;
      above += h;
    }
    s2[0] = b; s2[1] = above;
  }
  __syncthreads();
  int bin = s2[0];
  *above_out = s2[1];
  __syncthreads();
  return bin;
}

__global__ void __launch_bounds__(TPB, 4)
fused_kernel(const float* __restrict__ logits,
             const float* __restrict__ scores,
             const float* __restrict__ stop_logits,
             const int* __restrict__ batch,
             const int* __restrict__ cmask,
             float* __restrict__ out, int E, int NG)
{
  __shared__ int hist[4096];
  __shared__ int gsum[256];
  __shared__ int s2[2];
  __shared__ int sbounds[2];
  __shared__ unsigned int bin_u[BIN_CAP];
  __shared__ int bin_i[BIN_CAP];
  __shared__ int ab_i[KTOP];
  __shared__ int vidx[KTOP];
  __shared__ float vlog[KTOP];
  __shared__ int cnt_bin, cnt_ab, vcnt;
  __shared__ float sh_logden;
  __shared__ unsigned long long sh_kth;

  int tid = threadIdx.x;
  int g = blockIdx.x;

  // ---- segment bounds via binary search on sorted int32 batch ----
  if (tid < 2){
    int target = g + tid;
    int lo = 0, hi = E;
    while (lo < hi){
      int mid = (lo + hi) >> 1;
      if (batch[mid] < target) lo = mid + 1; else hi = mid;
    }
    sbounds[tid] = lo;
  }
  __syncthreads();
  int s = sbounds[0], e = sbounds[1];

  int q0 = s >> 2;
  int q1 = (e > s) ? ((e - 1) >> 2) : (q0 - 1);   // inclusive; empty seg -> none
  int qov = q0 + NIT * TPB;                       // start of (rare) overflow region
  const float4* sc4 = (const float4*)scores;
  const int4*   cm4 = (const int4*)cmask;
  const float4* lg4 = (const float4*)logits;

  // possibly-partial quad load (guards buffer end when E%4 != 0)
  auto ldq = [&](int q, float4& sc, int4& m){
    int base = q << 2;
    if (base + 3 < E){ sc = sc4[q]; m = cm4[q]; }
    else {
      sc = make_float4(0,0,0,0); m = make_int4(0,0,0,0);
      if (base + 0 < E){ sc.x = scores[base+0]; m.x = cmask[base+0]; }
      if (base + 1 < E){ sc.y = scores[base+1]; m.y = cmask[base+1]; }
      if (base + 2 < E){ sc.z = scores[base+2]; m.z = cmask[base+2]; }
    }
  };
  // scan the overflow region from memory (no-op for this dataset's segment sizes)
  auto mem_scan = [&](auto&& fn){
    for (int q = qov + tid; q <= q1; q += TPB){
      float4 sc; int4 m; ldq(q, sc, m);
      int base = q << 2;
      if (m.x && base+0 >= s && base+0 < e) fn(f2u(sc.x), base+0);
      if (m.y && base+1 >= s && base+1 < e) fn(f2u(sc.y), base+1);
      if (m.z && base+2 >= s && base+2 < e) fn(f2u(sc.z), base+2);
      if (m.w && base+3 >= s && base+3 < e) fn(f2u(sc.w), base+3);
    }
  };

  // ---- ONE memory scan: stage scores-u + validity into registers ----
  unsigned int su[NIT * 4];
  unsigned long long vm = 0ull;
  #pragma unroll
  for (int k = 0; k < NIT; ++k){
    int q = q0 + tid + k * TPB;
    float4 sc = make_float4(0,0,0,0); int4 m = make_int4(0,0,0,0);
    if (q <= q1) ldq(q, sc, m);
    int base = q << 2;
    su[k*4+0] = f2u(sc.x); if (q <= q1 && m.x && base+0 >= s && base+0 < e) vm |= 1ull << (k*4+0);
    su[k*4+1] = f2u(sc.y); if (q <= q1 && m.y && base+1 >= s && base+1 < e) vm |= 1ull << (k*4+1);
    su[k*4+2] = f2u(sc.z); if (q <= q1 && m.z && base+2 >= s && base+2 < e) vm |= 1ull << (k*4+2);
    su[k*4+3] = f2u(sc.w); if (q <= q1 && m.w && base+3 >= s && base+3 < e) vm |= 1ull << (k*4+3);
  }

  // ---- level-1 histogram (top 12 bits) from registers ----
  for (int b = tid; b < 4096; b += TPB) hist[b] = 0;
  __syncthreads();
  #pragma unroll
  for (int t2 = 0; t2 < NIT*4; ++t2)
    if ((vm >> t2) & 1ull) atomicAdd(&hist[su[t2] >> 20], 1);
  mem_scan([&](unsigned u, int){ atomicAdd(&hist[u >> 20], 1); });
  __syncthreads();

  int T = suffix_total(hist, 4096, gsum, tid);
  bool sel = (T > KTOP);
  unsigned int prefix = 0; int pshift = 32; int R = KTOP;
  if (sel){
    int above;
    int b1 = find_bin(hist, 4096, gsum, R, s2, tid, &above);
    R -= above; prefix = (unsigned)b1; pshift = 20;
    int hcnt = hist[b1];
    __syncthreads();
    if (hcnt > BIN_CAP){                     // rare: refine bits [19:8]
      for (int b = tid; b < 4096; b += TPB) hist[b] = 0;
      __syncthreads();
      #pragma unroll
      for (int t2 = 0; t2 < NIT*4; ++t2)
        if (((vm >> t2) & 1ull) && (su[t2] >> 20) == prefix)
          atomicAdd(&hist[(su[t2] >> 8) & 0xFFFu], 1);
      mem_scan([&](unsigned u, int){ if ((u >> 20) == prefix) atomicAdd(&hist[(u >> 8) & 0xFFFu], 1); });
      __syncthreads();
      suffix_total(hist, 4096, gsum, tid);
      int b2 = find_bin(hist, 4096, gsum, R, s2, tid, &above);
      R -= above; prefix = (prefix << 12) | (unsigned)b2; pshift = 8;
      hcnt = hist[b2];
      __syncthreads();
      if (hcnt > BIN_CAP){                   // rarer: final bits [7:0]
        for (int b = tid; b < 4096; b += TPB) hist[b] = 0;
        __syncthreads();
        #pragma unroll
        for (int t2 = 0; t2 < NIT*4; ++t2)
          if (((vm >> t2) & 1ull) && (su[t2] >> 8) == prefix)
            atomicAdd(&hist[su[t2] & 0xFFu], 1);
        mem_scan([&](unsigned u, int){ if ((u >> 8) == prefix) atomicAdd(&hist[u & 0xFFu], 1); });
        __syncthreads();
        suffix_total(hist, 256, gsum, tid);
        int b3 = find_bin(hist, 256, gsum, R, s2, tid, &above);
        R -= above; prefix = (prefix << 8) | (unsigned)b3; pshift = 0;
        __syncthreads();
      }
    }
  }

  // ---- collect pass (registers -> LDS): bin-matching + strictly-above ----
  if (tid == 0){ cnt_bin = 0; cnt_ab = 0; vcnt = 0; }
  __syncthreads();
  if (sel){
    #pragma unroll
    for (int k = 0; k < NIT; ++k){
      int qb = (q0 + tid + k * TPB) << 2;
      #pragma unroll
      for (int j = 0; j < 4; ++j){
        int t2 = k*4 + j;
        if ((vm >> t2) & 1ull){
          unsigned u = su[t2];
          unsigned hp = u >> pshift;
          if (hp == prefix){
            int sl = atomicAdd(&cnt_bin, 1);
            if (sl < BIN_CAP){ bin_u[sl] = u; bin_i[sl] = qb + j; }
          } else if (hp > prefix){
            int sl = atomicAdd(&cnt_ab, 1);
            if (sl < KTOP) ab_i[sl] = qb + j;   // above-count < R <= 32 always
          }
        }
      }
    }
    mem_scan([&](unsigned u, int idx){
      unsigned hp = u >> pshift;
      if (hp == prefix){
        int sl = atomicAdd(&cnt_bin, 1);
        if (sl < BIN_CAP){ bin_u[sl] = u; bin_i[sl] = idx; }
      } else if (hp > prefix){
        int sl = atomicAdd(&cnt_ab, 1);
        if (sl < KTOP) ab_i[sl] = idx;
      }
    });
  } else {
    #pragma unroll
    for (int k = 0; k < NIT; ++k){
      int qb = (q0 + tid + k * TPB) << 2;
      #pragma unroll
      for (int j = 0; j < 4; ++j){
        int t2 = k*4 + j;
        if ((vm >> t2) & 1ull){
          int sl = atomicAdd(&vcnt, 1);
          if (sl < KTOP) vidx[sl] = qb + j;     // T <= 32: all candidates valid
        }
      }
    }
    mem_scan([&](unsigned, int idx){
      int sl = atomicAdd(&vcnt, 1);
      if (sl < KTOP) vidx[sl] = idx;
    });
    if (tid == 0) sh_kth = 0ull;
  }
  __syncthreads();

  // ---- exact in-LDS ranking of the selected bin by 64-bit key ----
  if (sel){
    int bn = min(cnt_bin, BIN_CAP);
    for (int jj = tid; jj < bn; jj += TPB){
      unsigned long long kj = ((unsigned long long)bin_u[jj] << 32)
                            | (unsigned long long)(unsigned)(~(unsigned)bin_i[jj]);
      int rank = 0;
      for (int k = 0; k < bn; ++k){
        unsigned long long kk2 = ((unsigned long long)bin_u[k] << 32)
                               | (unsigned long long)(unsigned)(~(unsigned)bin_i[k]);
        rank += (kk2 > kj) ? 1 : 0;
      }
      if (rank < R){
        int sl = atomicAdd(&vcnt, 1);
        if (sl < KTOP) vidx[sl] = bin_i[jj];
      }
      if (rank == R - 1) sh_kth = kj;          // unique writer (keys distinct)
    }
    int na = min(cnt_ab, KTOP);
    for (int jj = tid; jj < na; jj += TPB){
      int sl = atomicAdd(&vcnt, 1);
      if (sl < KTOP) vidx[sl] = ab_i[jj];
    }
  }
  __syncthreads();

  // ---- LSE over <=32 valid logits ----
  int c = min(vcnt, KTOP);
  if (tid < c) vlog[tid] = logits[vidx[tid]];
  __syncthreads();
  if (tid == 0){
    float stop = stop_logits[g];               // TEMP == 1.0
    float logden;
    if (c == 0){
      logden = stop;
    } else {
      float m = -FLT_MAX;
      for (int j2 = 0; j2 < c; ++j2) m = fmaxf(m, vlog[j2]);
      float sum = 0.f;
      for (int j2 = 0; j2 < c; ++j2) sum += expf(vlog[j2] - m);
      float lse = logf(fmaxf(sum, FLT_EPSILON)) + m;   // eps clamp per reference
      float mx = fmaxf(lse, stop);
      float dd = fabsf(lse - stop);
      logden = mx + log1pf(expf(-dd));         // logaddexp(lse, stop)
    }
    sh_logden = logden;
  }
  __syncthreads();
  float logden = sh_logden;
  unsigned long long kk = sh_kth;
  const float SENT = __uint_as_float(SENT_U32);

  auto oval = [&](bool vbit, unsigned u, int idx, float lgv) -> float {
    float o = SENT;
    if (vbit){
      unsigned long long key = ((unsigned long long)u << 32)
                             | (unsigned long long)(unsigned)(~(unsigned)idx);
      if (key >= kk){
        float val = lgv - logden;
        if (!(val >= -VCLAMP)) val = -VCLAMP;  // also flushes NaN
        if (val > VCLAMP)      val =  VCLAMP;
        o = val;
      }
    }
    return o;
  };

  // ---- output pass: validity from registers; logits read + store only ----
  #pragma unroll
  for (int k = 0; k < NIT; ++k){
    int q = q0 + tid + k * TPB;
    if (q <= q1){
      int base = q << 2;
      float4 lg;
      if (base + 3 < E) lg = lg4[q];
      else {
        lg = make_float4(0,0,0,0);
        if (base+0 < E) lg.x = logits[base+0];
        if (base+1 < E) lg.y = logits[base+1];
        if (base+2 < E) lg.z = logits[base+2];
      }
      float o0 = oval((vm >> (k*4+0)) & 1ull, su[k*4+0], base+0, lg.x);
      float o1 = oval((vm >> (k*4+1)) & 1ull, su[k*4+1], base+1, lg.y);
      float o2 = oval((vm >> (k*4+2)) & 1ull, su[k*4+2], base+2, lg.z);
      float o3 = oval((vm >> (k*4+3)) & 1ull, su[k*4+3], base+3, lg.w);
      if (base >= s && base + 3 < e){
        ((float4*)out)[q] = make_float4(o0, o1, o2, o3);
      } else {
        if (base+0 >= s && base+0 < e) out[base+0] = o0;
        if (base+1 >= s && base+1 < e) out[base+1] = o1;
        if (base+2 >= s && base+2 < e) out[base+2] = o2;
        if (base+3 >= s && base+3 < e) out[base+3] = o3;
      }
    }
  }
  // overflow region (memory-based; no-op for expected segment sizes)
  for (int q = qov + tid; q <= q1; q += TPB){
    float4 sc; int4 m; ldq(q, sc, m);
    int base = q << 2;
    float4 lg;
    if (base + 3 < E) lg = lg4[q];
    else {
      lg = make_float4(0,0,0,0);
      if (base+0 < E) lg.x = logits[base+0];
      if (base+1 < E) lg.y = logits[base+1];
      if (base+2 < E) lg.z = logits[base+2];
    }
    float o0 = oval(m.x && base+0 >= s && base+0 < e, f2u(sc.x), base+0, lg.x);
    float o1 = oval(m.y && base+1 >= s && base+1 < e, f2u(sc.y), base+1, lg.y);
    float o2 = oval(m.z && base+2 >= s && base+2 < e, f2u(sc.z), base+2, lg.z);
    float o3 = oval(m.w && base+3 >= s && base+3 < e, f2u(sc.w), base+3, lg.w);
    if (base >= s && base + 3 < e){
      ((float4*)out)[q] = make_float4(o0, o1, o2, o3);
    } else {
      if (base+0 >= s && base+0 < e) out[base+0] = o0;
      if (base+1 >= s && base+1 < e) out[base+1] = o1;
      if (base+2 >= s && base+2 < e) out[base+2] = o2;
      if (base+3 >= s && base+3 < e) out[base+3] = o3;
    }
  }
}

extern "C" void kernel_launch(void* const* d_in, const int* in_sizes, int n_in,
                              void* d_out, int out_size, void* d_ws, size_t ws_size,
                              hipStream_t stream){
  const float* edge_logits = (const float*)d_in[0];
  const float* edge_scores = (const float*)d_in[1];
  const float* stop_logits = (const float*)d_in[2];
  const int*   edge_batch  = (const int*)d_in[3];
  const int*   cmask       = (const int*)d_in[4];
  int E  = in_sizes[0];
  int NG = in_sizes[2];
  float* out = (float*)d_out;
  (void)d_ws; (void)ws_size;

  hipLaunchKernelGGL(fused_kernel, dim3(NG), dim3(TPB), 0, stream,
                     edge_logits, edge_scores, stop_logits, edge_batch, cmask,
                     out, E, NG);
}

// Round 9
// 264.252 us; speedup vs baseline: 1.1621x; 1.1621x over previous
//
#include <hip/hip_runtime.h>
#include <float.h>

#define TPB 512
#define KTOP 32
#define BIN_CAP 1024

// Output buffer is f32; harness compares after bf16-casting both sides.
// Sentinel must bf16-round FINITE: 0xFF7F0000 -> bf16 0xFF7F (largest finite neg).
#define SENT_U32 0xFF7F0000u
#define VCLAMP 3.0e38f

__device__ __forceinline__ unsigned int f2u(float f){
  unsigned int u = __float_as_uint(f);
  return (u & 0x80000000u) ? ~u : (u | 0x80000000u);
}

// suffix-sum of hist by 256 groups into gsum; returns total. TPB may exceed 256.
__device__ int suffix_total(int* hist, int NB, int* gsum, int tid){
  int GS = NB >> 8;
  if (tid < 256){
    int p = 0, base = tid * GS;
    for (int j = 0; j < GS; ++j) p += hist[base + j];
    gsum[tid] = p;
  }
  __syncthreads();
  for (int d = 1; d < 256; d <<= 1){
    int v = 0;
    if (tid < 256 && tid + d < 256) v = gsum[tid + d];
    __syncthreads();
    if (tid < 256) gsum[tid] += v;
    __syncthreads();
  }
  return gsum[0];
}

// find bin b with above(b) < R <= above(b)+hist[b]; requires 1 <= R <= gsum[0]
__device__ int find_bin(int* hist, int NB, int* gsum, int R, int* s2, int tid,
                        int* above_out){
  int GS = NB >> 8;
  if (tid < 256){
    int St  = gsum[tid];
    int St1 = (tid < 255) ? gsum[tid + 1] : 0;
    if (R > St1 && R <= St) s2[0] = tid;   // unique writer (gsum non-increasing)
  }
  __syncthreads();
  if (tid == 0){
    int G = s2[0];
    int above = (G < 255) ? gsum[G + 1] : 0;
    int b = (G + 1) * GS - 1;
    for (; b > G * GS; --b){
      int h = hist[b];
      if (above + h >= R) break;
      above += h;
    }
    s2[0] = b; s2[1] = above;
  }
  __syncthreads();
  int bin = s2[0];
  *above_out = s2[1];
  __syncthreads();
  return bin;
}

__global__ void __launch_bounds__(TPB, 4)
fused_kernel(const float* __restrict__ logits,
             const float* __restrict__ scores,
             const float* __restrict__ stop_logits,
             const int* __restrict__ batch,
             const int* __restrict__ cmask,
             float* __restrict__ out, int E, int NG)
{
  __shared__ int hist[4096];
  __shared__ int gsum[256];
  __shared__ int s2[2];
  __shared__ int sbounds[2];
  __shared__ unsigned int bin_u[BIN_CAP];
  __shared__ int bin_i[BIN_CAP];
  __shared__ int ab_i[KTOP];
  __shared__ int vidx[KTOP];
  __shared__ float vlog[KTOP];
  __shared__ int cnt_bin, cnt_ab, vcnt;
  __shared__ float sh_logden;

  int tid = threadIdx.x;
  int g = blockIdx.x;

  // ---- segment bounds via binary search on sorted int32 batch ----
  if (tid < 2){
    int target = g + tid;
    int lo = 0, hi = E;
    while (lo < hi){
      int mid = (lo + hi) >> 1;
      if (batch[mid] < target) lo = mid + 1; else hi = mid;
    }
    sbounds[tid] = lo;
  }
  __syncthreads();
  int s = sbounds[0], e = sbounds[1];
  int s4 = (s + 3) & ~3; if (s4 > e) s4 = e;
  int e4 = e & ~3;       if (e4 < s4) e4 = s4;
  const int4*   cm4 = (const int4*)cmask;
  const float4* sc4 = (const float4*)scores;

  // vectorized scan of (cmask, scores, idx) over [s,e)
  auto scan = [&](auto&& fn){
    int i = s + tid;  if (i < s4) fn(cmask[i], scores[i], i);
    int j = e4 + tid; if (j < e)  fn(cmask[j], scores[j], j);
    for (int q = (s4 >> 2) + tid, qe = (e4 >> 2); q < qe; q += TPB){
      int4 m = cm4[q]; float4 sc = sc4[q];
      int base = q << 2;
      fn(m.x, sc.x, base);     fn(m.y, sc.y, base + 1);
      fn(m.z, sc.z, base + 2); fn(m.w, sc.w, base + 3);
    }
  };

  // ---- scan 1: level-1 histogram (top 12 bits) ----
  for (int b = tid; b < 4096; b += TPB) hist[b] = 0;
  __syncthreads();
  scan([&](int m, float sc, int){ if (m) atomicAdd(&hist[f2u(sc) >> 20], 1); });
  __syncthreads();

  int T = suffix_total(hist, 4096, gsum, tid);
  bool sel = (T > KTOP);
  unsigned int prefix = 0; int pshift = 32; int R = KTOP;
  if (sel){
    int above;
    int b1 = find_bin(hist, 4096, gsum, R, s2, tid, &above);
    R -= above; prefix = (unsigned)b1; pshift = 20;
    int hcnt = hist[b1];
    __syncthreads();
    if (hcnt > BIN_CAP){                     // rare: refine bits [19:8]
      for (int b = tid; b < 4096; b += TPB) hist[b] = 0;
      __syncthreads();
      scan([&](int m, float sc, int){
        if (m){ unsigned u = f2u(sc);
          if ((u >> 20) == prefix) atomicAdd(&hist[(u >> 8) & 0xFFFu], 1); }
      });
      __syncthreads();
      suffix_total(hist, 4096, gsum, tid);
      int b2 = find_bin(hist, 4096, gsum, R, s2, tid, &above);
      R -= above; prefix = (prefix << 12) | (unsigned)b2; pshift = 8;
      hcnt = hist[b2];
      __syncthreads();
      if (hcnt > BIN_CAP){                   // rarer: final bits [7:0]
        for (int b = tid; b < 256; b += TPB) hist[b] = 0;
        __syncthreads();
        scan([&](int m, float sc, int){
          if (m){ unsigned u = f2u(sc);
            if ((u >> 8) == prefix) atomicAdd(&hist[u & 0xFFu], 1); }
        });
        __syncthreads();
        suffix_total(hist, 256, gsum, tid);
        int b3 = find_bin(hist, 256, gsum, R, s2, tid, &above);
        R -= above; prefix = (prefix << 8) | (unsigned)b3; pshift = 0;
        __syncthreads();
      }
    }
  }

  // ---- scan 2: collect bin-matching (u,idx) + strictly-above idx ----
  if (tid == 0){ cnt_bin = 0; cnt_ab = 0; vcnt = 0; }
  __syncthreads();
  if (sel){
    scan([&](int m, float sc, int idx){
      if (m){
        unsigned u = f2u(sc);
        unsigned hp = u >> pshift;
        if (hp == prefix){
          int sl = atomicAdd(&cnt_bin, 1);
          if (sl < BIN_CAP){ bin_u[sl] = u; bin_i[sl] = idx; }
        } else if (hp > prefix){
          int sl = atomicAdd(&cnt_ab, 1);
          if (sl < KTOP) ab_i[sl] = idx;     // above-count < R <= 32 always
        }
      }
    });
  } else {
    scan([&](int m, float, int idx){
      if (m){
        int sl = atomicAdd(&vcnt, 1);
        if (sl < KTOP) vidx[sl] = idx;       // T <= 32: all candidates valid
      }
    });
  }
  __syncthreads();

  // ---- exact in-LDS ranking of the bin by 64-bit (u, ~idx) key ----
  if (sel){
    int bn = min(cnt_bin, BIN_CAP);
    for (int jj = tid; jj < bn; jj += TPB){
      unsigned long long kj = ((unsigned long long)bin_u[jj] << 32)
                            | (unsigned long long)(unsigned)(~(unsigned)bin_i[jj]);
      int rank = 0;
      for (int k = 0; k < bn; ++k){
        unsigned long long kk2 = ((unsigned long long)bin_u[k] << 32)
                               | (unsigned long long)(unsigned)(~(unsigned)bin_i[k]);
        rank += (kk2 > kj) ? 1 : 0;
      }
      if (rank < R){
        int sl = atomicAdd(&vcnt, 1);
        if (sl < KTOP) vidx[sl] = bin_i[jj];
      }
    }
    int na = min(cnt_ab, KTOP);
    for (int jj = tid; jj < na; jj += TPB){
      int sl = atomicAdd(&vcnt, 1);
      if (sl < KTOP) vidx[sl] = ab_i[jj];
    }
    __syncthreads();
  }

  // ---- LSE over the <=32 valid logits (32 scalar loads, no scan) ----
  int c = min(vcnt, KTOP);
  if (tid < c) vlog[tid] = logits[vidx[tid]];
  __syncthreads();
  if (tid == 0){
    float stop = stop_logits[g];             // TEMP == 1.0
    float logden;
    if (c == 0){
      logden = stop;                         // logaddexp(~-inf, stop) = stop
    } else {
      float m = -FLT_MAX;
      for (int j2 = 0; j2 < c; ++j2) m = fmaxf(m, vlog[j2]);
      float sum = 0.f;
      for (int j2 = 0; j2 < c; ++j2) sum += expf(vlog[j2] - m);
      float lse = logf(fmaxf(sum, FLT_EPSILON)) + m;   // eps clamp per reference
      float mx = fmaxf(lse, stop);
      float dd = fabsf(lse - stop);
      logden = mx + log1pf(expf(-dd));       // logaddexp(lse, stop)
    }
    sh_logden = logden;
  }

  // ---- fill pass: stream sentinel over [s,e) — zero reads ----
  const float SENT = __uint_as_float(SENT_U32);
  {
    int i = s + tid;  if (i < s4) out[i] = SENT;
    int j = e4 + tid; if (j < e)  out[j] = SENT;
    float4 sv = make_float4(SENT, SENT, SENT, SENT);
    for (int q = (s4 >> 2) + tid, qe = (e4 >> 2); q < qe; q += TPB)
      ((float4*)out)[q] = sv;
  }
  __syncthreads();   // fill complete + sh_logden visible

  // ---- scatter the <=32 valid log-probs ----
  if (tid < c){
    float val = vlog[tid] - sh_logden;
    if (!(val >= -VCLAMP)) val = -VCLAMP;    // flushes NaN too
    if (val > VCLAMP)      val =  VCLAMP;
    out[vidx[tid]] = val;
  }
}

extern "C" void kernel_launch(void* const* d_in, const int* in_sizes, int n_in,
                              void* d_out, int out_size, void* d_ws, size_t ws_size,
                              hipStream_t stream){
  const float* edge_logits = (const float*)d_in[0];
  const float* edge_scores = (const float*)d_in[1];
  const float* stop_logits = (const float*)d_in[2];
  const int*   edge_batch  = (const int*)d_in[3];
  const int*   cmask       = (const int*)d_in[4];
  int E  = in_sizes[0];
  int NG = in_sizes[2];
  float* out = (float*)d_out;
  (void)d_ws; (void)ws_size;

  hipLaunchKernelGGL(fused_kernel, dim3(NG), dim3(TPB), 0, stream,
                     edge_logits, edge_scores, stop_logits, edge_batch, cmask,
                     out, E, NG);
}

// Round 10
// 263.734 us; speedup vs baseline: 1.1644x; 1.0020x over previous
//
#include <hip/hip_runtime.h>
#include <float.h>

#define TPB 256
#define KTOP 32
#define BIN_CAP 512
#define BMAP_WORDS 1024   // 32768 candidacy bits per segment; global fallback beyond

// Output buffer is f32; harness compares after bf16-casting both sides.
// Sentinel must bf16-round FINITE: 0xFF7F0000 -> bf16 0xFF7F (largest finite neg).
#define SENT_U32 0xFF7F0000u
#define VCLAMP 3.0e38f

__device__ __forceinline__ unsigned int f2u(float f){
  unsigned int u = __float_as_uint(f);
  return (u & 0x80000000u) ? ~u : (u | 0x80000000u);
}

// suffix-sum of hist by 256 groups into gsum; returns total (TPB == 256)
__device__ int suffix_total(int* hist, int NB, int* gsum, int tid){
  int GS = NB >> 8;
  int p = 0, base = tid * GS;
  for (int j = 0; j < GS; ++j) p += hist[base + j];
  gsum[tid] = p;
  __syncthreads();
  for (int d = 1; d < 256; d <<= 1){
    int v = (tid + d < 256) ? gsum[tid + d] : 0;
    __syncthreads();
    gsum[tid] += v;
    __syncthreads();
  }
  return gsum[0];
}

// find bin b with above(b) < R <= above(b)+hist[b]; requires 1 <= R <= gsum[0]
__device__ int find_bin(int* hist, int NB, int* gsum, int R, int* s2, int tid,
                        int* above_out){
  int GS = NB >> 8;
  int St  = gsum[tid];
  int St1 = (tid < 255) ? gsum[tid + 1] : 0;
  if (R > St1 && R <= St) s2[0] = tid;   // unique writer (gsum non-increasing)
  __syncthreads();
  if (tid == 0){
    int G = s2[0];
    int above = (G < 255) ? gsum[G + 1] : 0;
    int b = (G + 1) * GS - 1;
    for (; b > G * GS; --b){
      int h = hist[b];
      if (above + h >= R) break;
      above += h;
    }
    s2[0] = b; s2[1] = above;
  }
  __syncthreads();
  int bin = s2[0];
  *above_out = s2[1];
  __syncthreads();
  return bin;
}

__global__ void __launch_bounds__(TPB, 8)
fused_kernel(const float* __restrict__ logits,
             const float* __restrict__ scores,
             const float* __restrict__ stop_logits,
             const int* __restrict__ batch,
             const int* __restrict__ cmask,
             float* __restrict__ out, int E, int NG)
{
  __shared__ int hist[2048];
  __shared__ int gsum[256];
  __shared__ int s2[2];
  __shared__ int sbounds[2];
  __shared__ unsigned int bmap[BMAP_WORDS];
  __shared__ unsigned int bin_u[BIN_CAP];
  __shared__ int bin_i[BIN_CAP];
  __shared__ int ab_i[KTOP];
  __shared__ int vidx[KTOP];
  __shared__ float vlog[KTOP];
  __shared__ int cnt_bin, cnt_ab, vcnt;
  __shared__ float sh_logden;

  int tid = threadIdx.x;
  int g = blockIdx.x;

  // ---- segment bounds via binary search on sorted int32 batch ----
  if (tid < 2){
    int target = g + tid;
    int lo = 0, hi = E;
    while (lo < hi){
      int mid = (lo + hi) >> 1;
      if (batch[mid] < target) lo = mid + 1; else hi = mid;
    }
    sbounds[tid] = lo;
  }
  __syncthreads();
  int s = sbounds[0], e = sbounds[1];
  int s4 = (s + 3) & ~3; if (s4 > e) s4 = e;
  int e4 = e & ~3;       if (e4 < s4) e4 = s4;
  const int4*   cm4 = (const int4*)cmask;
  const float4* sc4 = (const float4*)scores;

  // ---- init LDS ----
  for (int b = tid; b < 2048; b += TPB) hist[b] = 0;
  for (int w = tid; w < BMAP_WORDS; w += TPB) bmap[w] = 0;
  if (tid == 0){ cnt_bin = 0; cnt_ab = 0; vcnt = 0; }
  __syncthreads();

  const float SENT = __uint_as_float(SENT_U32);

  // ---- scan 1 (the ONLY cmask read) + sentinel fill + candidacy bitmap ----
  auto p1 = [&](int m, float sc, int idx){
    if (m){
      unsigned u = f2u(sc);
      atomicAdd(&hist[u >> 21], 1);
      int rel = idx - s;
      if (rel < BMAP_WORDS * 32) atomicOr(&bmap[rel >> 5], 1u << (rel & 31));
    }
  };
  {
    int i = s + tid;  if (i < s4){ p1(cmask[i], scores[i], i); out[i] = SENT; }
    int j = e4 + tid; if (j < e) { p1(cmask[j], scores[j], j); out[j] = SENT; }
    float4 sv = make_float4(SENT, SENT, SENT, SENT);
    for (int q = (s4 >> 2) + tid, qe = (e4 >> 2); q < qe; q += TPB){
      int4 m = cm4[q]; float4 sc = sc4[q];
      int base = q << 2;
      p1(m.x, sc.x, base);     p1(m.y, sc.y, base + 1);
      p1(m.z, sc.z, base + 2); p1(m.w, sc.w, base + 3);
      ((float4*)out)[q] = sv;
    }
  }
  __syncthreads();

  // candidacy: bitmap within range, global cmask beyond (rare huge segments)
  auto is_cand = [&](int idx) -> bool {
    int rel = idx - s;
    if (rel < BMAP_WORDS * 32) return (bmap[rel >> 5] >> (rel & 31)) & 1u;
    return cmask[idx] != 0;
  };
  // scores-only vectorized scan
  auto scan_sc = [&](auto&& fn){
    int i = s + tid;  if (i < s4) fn(scores[i], i);
    int j = e4 + tid; if (j < e)  fn(scores[j], j);
    for (int q = (s4 >> 2) + tid, qe = (e4 >> 2); q < qe; q += TPB){
      float4 sc = sc4[q];
      int base = q << 2;
      fn(sc.x, base);     fn(sc.y, base + 1);
      fn(sc.z, base + 2); fn(sc.w, base + 3);
    }
  };

  // ---- radix control: find the 11-bit (then deeper) prefix holding rank K ----
  int T = suffix_total(hist, 2048, gsum, tid);
  bool sel = (T > KTOP);
  unsigned int prefix = 0; int pshift = 32; int R = KTOP;
  if (sel){
    int above;
    int b1 = find_bin(hist, 2048, gsum, R, s2, tid, &above);
    R -= above; prefix = (unsigned)b1; pshift = 21;
    int hcnt = hist[b1];
    __syncthreads();
    if (hcnt > BIN_CAP){                      // rare: refine bits [20:10]
      for (int b = tid; b < 2048; b += TPB) hist[b] = 0;
      __syncthreads();
      scan_sc([&](float sc, int idx){
        unsigned u = f2u(sc);
        if ((u >> 21) == prefix && is_cand(idx))
          atomicAdd(&hist[(u >> 10) & 0x7FFu], 1);
      });
      __syncthreads();
      suffix_total(hist, 2048, gsum, tid);
      int b2 = find_bin(hist, 2048, gsum, R, s2, tid, &above);
      R -= above; prefix = (prefix << 11) | (unsigned)b2; pshift = 10;
      hcnt = hist[b2];
      __syncthreads();
      if (hcnt > BIN_CAP){                    // rarer: final bits [9:0]
        for (int b = tid; b < 1024; b += TPB) hist[b] = 0;
        __syncthreads();
        scan_sc([&](float sc, int idx){
          unsigned u = f2u(sc);
          if ((u >> 10) == prefix && is_cand(idx))
            atomicAdd(&hist[u & 0x3FFu], 1);
        });
        __syncthreads();
        suffix_total(hist, 1024, gsum, tid);
        int b3 = find_bin(hist, 1024, gsum, R, s2, tid, &above);
        R -= above; prefix = (prefix << 10) | (unsigned)b3; pshift = 0;
        __syncthreads();
      }
    }
  }

  // ---- scan 2 (scores only) / bitmap walk: gather candidates at/above prefix ----
  if (sel){
    scan_sc([&](float sc, int idx){
      unsigned u = f2u(sc);
      unsigned hp = (pshift < 32) ? (u >> pshift) : 0u;
      if (hp >= prefix){
        if (is_cand(idx)){
          if (hp == prefix){
            int sl = atomicAdd(&cnt_bin, 1);
            if (sl < BIN_CAP){ bin_u[sl] = u; bin_i[sl] = idx; }
          } else {
            int sl = atomicAdd(&cnt_ab, 1);
            if (sl < KTOP) ab_i[sl] = idx;    // strictly-above count < R <= 32
          }
        }
      }
    });
    __syncthreads();
    // exact in-LDS ranking of the bin by 64-bit (u, ~idx) key
    int bn = min(cnt_bin, BIN_CAP);
    for (int jj = tid; jj < bn; jj += TPB){
      unsigned long long kj = ((unsigned long long)bin_u[jj] << 32)
                            | (unsigned long long)(unsigned)(~(unsigned)bin_i[jj]);
      int rank = 0;
      for (int k = 0; k < bn; ++k){
        unsigned long long kk2 = ((unsigned long long)bin_u[k] << 32)
                               | (unsigned long long)(unsigned)(~(unsigned)bin_i[k]);
        rank += (kk2 > kj) ? 1 : 0;
      }
      if (rank < R){
        int sl = atomicAdd(&vcnt, 1);
        if (sl < KTOP) vidx[sl] = bin_i[jj];
      }
    }
    int na = min(cnt_ab, KTOP);
    for (int jj = tid; jj < na; jj += TPB){
      int sl = atomicAdd(&vcnt, 1);
      if (sl < KTOP) vidx[sl] = ab_i[jj];
    }
  } else {
    // T <= 32: every candidate is valid — walk the bitmap, no memory scan
    int n = e - s;
    int nw = (n + 31) >> 5; if (nw > BMAP_WORDS) nw = BMAP_WORDS;
    for (int w = tid; w < nw; w += TPB){
      unsigned bits = bmap[w];
      while (bits){
        int b = __ffs((int)bits) - 1;
        bits &= bits - 1;
        int sl = atomicAdd(&vcnt, 1);
        if (sl < KTOP) vidx[sl] = s + (w << 5) + b;
      }
    }
    for (int i = s + BMAP_WORDS * 32 + tid; i < e; i += TPB){
      if (cmask[i]){
        int sl = atomicAdd(&vcnt, 1);
        if (sl < KTOP) vidx[sl] = i;
      }
    }
  }
  __syncthreads();

  // ---- LSE over the <=32 valid logits (scalar loads, no scan) ----
  int c = min(vcnt, KTOP);
  if (tid < c) vlog[tid] = logits[vidx[tid]];
  __syncthreads();
  if (tid == 0){
    float stop = stop_logits[g];              // TEMP == 1.0
    float logden;
    if (c == 0){
      logden = stop;                          // logaddexp(~-inf, stop) = stop
    } else {
      float m = -FLT_MAX;
      for (int j2 = 0; j2 < c; ++j2) m = fmaxf(m, vlog[j2]);
      float sum = 0.f;
      for (int j2 = 0; j2 < c; ++j2) sum += expf(vlog[j2] - m);
      float lse = logf(fmaxf(sum, FLT_EPSILON)) + m;   // eps clamp per reference
      float mx = fmaxf(lse, stop);
      float dd = fabsf(lse - stop);
      logden = mx + log1pf(expf(-dd));        // logaddexp(lse, stop)
    }
    sh_logden = logden;
  }
  __syncthreads();

  // ---- scatter the <=32 valid log-probs over the sentinel fill ----
  if (tid < c){
    float val = vlog[tid] - sh_logden;
    if (!(val >= -VCLAMP)) val = -VCLAMP;     // flushes NaN too
    if (val > VCLAMP)      val =  VCLAMP;
    out[vidx[tid]] = val;
  }
}

extern "C" void kernel_launch(void* const* d_in, const int* in_sizes, int n_in,
                              void* d_out, int out_size, void* d_ws, size_t ws_size,
                              hipStream_t stream){
  const float* edge_logits = (const float*)d_in[0];
  const float* edge_scores = (const float*)d_in[1];
  const float* stop_logits = (const float*)d_in[2];
  const int*   edge_batch  = (const int*)d_in[3];
  const int*   cmask       = (const int*)d_in[4];
  int E  = in_sizes[0];
  int NG = in_sizes[2];
  float* out = (float*)d_out;
  (void)d_ws; (void)ws_size;

  hipLaunchKernelGGL(fused_kernel, dim3(NG), dim3(TPB), 0, stream,
                     edge_logits, edge_scores, stop_logits, edge_batch, cmask,
                     out, E, NG);
}